// Round 3
// baseline (276.618 us; speedup 1.0000x reference)
//
#include <hip/hip_runtime.h>

#define B_DIM 32768
#define IN_DIM 1024
#define OUT_DIM 1024

typedef int v4i __attribute__((ext_vector_type(4)));
typedef int v16i __attribute__((ext_vector_type(16)));

__device__ __forceinline__ int sgnb(float v) {
    return (v > 0.f) ? 1 : ((v < 0.f) ? 0xff : 0);
}

// gated sign: mask = (sign(g)+1)/2 in {0,.5,1}; sign(w*mask) = (g<0) ? 0 : sign(w)
__device__ __forceinline__ int gsgnb(float w, float g) {
    return (g < 0.f) ? 0 : sgnb(w);
}

// Blocks [0, 8192): binarize x rows (4 rows/block, 1 wave/row) + in_scale.
// Blocks [8192, 8448): binarize weight*gate rows + weight_scale.
__global__ __launch_bounds__(256) void prep_kernel(
    const float* __restrict__ x, const float* __restrict__ w,
    const float* __restrict__ g,
    signed char* __restrict__ sx, signed char* __restrict__ wb,
    float* __restrict__ xscale, float* __restrict__ wscale) {
    const int wave = threadIdx.x >> 6;
    const int lane = threadIdx.x & 63;
    const int bq = blockIdx.x;
    if (bq < B_DIM / 4) {
        const int row = bq * 4 + wave;
        const float4* xr = (const float4*)(x + (size_t)row * IN_DIM);
        int* sr = (int*)(sx + (size_t)row * IN_DIM);
        float asum = 0.f;
#pragma unroll
        for (int it = 0; it < 4; ++it) {
            float4 v = xr[it * 64 + lane];
            asum += fabsf(v.x) + fabsf(v.y) + fabsf(v.z) + fabsf(v.w);
            sr[it * 64 + lane] =
                sgnb(v.x) | (sgnb(v.y) << 8) | (sgnb(v.z) << 16) | (sgnb(v.w) << 24);
        }
#pragma unroll
        for (int off = 32; off >= 1; off >>= 1) asum += __shfl_xor(asum, off, 64);
        if (lane == 0) xscale[row] = asum * (1.0f / IN_DIM);
    } else {
        const int row = (bq - B_DIM / 4) * 4 + wave;
        const float4* wr = (const float4*)(w + (size_t)row * IN_DIM);
        const float4* gr = (const float4*)(g + (size_t)row * IN_DIM);
        int* sr = (int*)(wb + (size_t)row * IN_DIM);
        float asum = 0.f;
#pragma unroll
        for (int it = 0; it < 4; ++it) {
            float4 wv = wr[it * 64 + lane];
            float4 gv = gr[it * 64 + lane];
            asum += fabsf(wv.x) + fabsf(wv.y) + fabsf(wv.z) + fabsf(wv.w);
            sr[it * 64 + lane] = gsgnb(wv.x, gv.x) | (gsgnb(wv.y, gv.y) << 8) |
                                 (gsgnb(wv.z, gv.z) << 16) | (gsgnb(wv.w, gv.w) << 24);
        }
#pragma unroll
        for (int off = 32; off >= 1; off >>= 1) asum += __shfl_xor(asum, off, 64);
        if (lane == 0) wscale[row] = asum * (1.0f / IN_DIM);
    }
}

// i8 GEMM: 128x128 tile, BK=64, 4 waves (2x2), wave sub-tile 64x64 = 2x2 frags
// of mfma_i32_32x32x32_i8. Double-buffered LDS, stage(t+1) issued before
// compute(t), sync via __syncthreads only (race-safe). XCD swizzle. Epilogue
// fuses in_scale * weight_scale * (acc + bias).
__global__ __launch_bounds__(256) void gemm_i8_kernel(
    const signed char* __restrict__ A,   // [B_DIM][IN] sign(x)
    const signed char* __restrict__ Bw,  // [OUT][IN]   gated sign(w)
    const float* __restrict__ xscale,    // [B_DIM]
    const float* __restrict__ wscale,    // [OUT]
    const float* __restrict__ bias,      // [OUT]
    float* __restrict__ out) {           // [B_DIM][OUT]
    __shared__ signed char smA[2][128 * 64];  // 2 x 8 KB, 64 B rows
    __shared__ signed char smB[2][128 * 64];

    const int t = threadIdx.x;
    const int wave = t >> 6, lane = t & 63;
    // XCD-aware bijective swizzle: 2048 blocks = 8 XCDs x 256-chunk.
    const int swz = (blockIdx.x & 7) * 256 + (blockIdx.x >> 3);
    const int bm = swz >> 3;  // 256 tiles along M
    const int bn = swz & 7;   // 8 tiles along N
    const int wr = wave >> 1, wc = wave & 1;

    const v16i vzero = {0, 0, 0, 0, 0, 0, 0, 0, 0, 0, 0, 0, 0, 0, 0, 0};
    v16i acc[2][2];
#pragma unroll
    for (int m = 0; m < 2; ++m)
#pragma unroll
        for (int n = 0; n < 2; ++n) acc[m][n] = vzero;

    const int r32 = lane & 31;        // fragment row/col within 32
    const int kh = (lane >> 5) * 16;  // 16-byte k-half within 32-byte k-sub
    const size_t arow0 = (size_t)bm * 128;
    const size_t brow0 = (size_t)bn * 128;
    // per-lane staging coords (LDS dest is wave-uniform base + lane*16)
    const int l_loff0 = wave * 1024;            // c=0 wave base
    const int l_loff1 = 4096 + wave * 1024;     // c=1 wave base
    const int srow0 = (l_loff0 + lane * 16) >> 6, scol0 = (l_loff0 + lane * 16) & 63;
    const int srow1 = (l_loff1 + lane * 16) >> 6, scol1 = (l_loff1 + lane * 16) & 63;

#define STAGE(BUF, K0)                                                          \
    do {                                                                        \
        __builtin_amdgcn_global_load_lds(                                       \
            (const __attribute__((address_space(1))) void*)(                    \
                A + (arow0 + srow0) * (size_t)IN_DIM + (K0) + scol0),           \
            (__attribute__((address_space(3))) void*)(smA[BUF] + l_loff0), 16, 0, 0); \
        __builtin_amdgcn_global_load_lds(                                       \
            (const __attribute__((address_space(1))) void*)(                    \
                Bw + (brow0 + srow0) * (size_t)IN_DIM + (K0) + scol0),          \
            (__attribute__((address_space(3))) void*)(smB[BUF] + l_loff0), 16, 0, 0); \
        __builtin_amdgcn_global_load_lds(                                       \
            (const __attribute__((address_space(1))) void*)(                    \
                A + (arow0 + srow1) * (size_t)IN_DIM + (K0) + scol1),           \
            (__attribute__((address_space(3))) void*)(smA[BUF] + l_loff1), 16, 0, 0); \
        __builtin_amdgcn_global_load_lds(                                       \
            (const __attribute__((address_space(1))) void*)(                    \
                Bw + (brow0 + srow1) * (size_t)IN_DIM + (K0) + scol1),          \
            (__attribute__((address_space(3))) void*)(smB[BUF] + l_loff1), 16, 0, 0); \
    } while (0)

#define COMPUTE(BUF)                                                            \
    do {                                                                        \
        _Pragma("unroll")                                                       \
        for (int ks = 0; ks < 2; ++ks) {                                        \
            v4i af[2], bf[2];                                                   \
            _Pragma("unroll")                                                   \
            for (int m = 0; m < 2; ++m)                                         \
                af[m] = *(const v4i*)(smA[BUF] +                                \
                        (wr * 64 + m * 32 + r32) * 64 + ks * 32 + kh);          \
            _Pragma("unroll")                                                   \
            for (int n = 0; n < 2; ++n)                                         \
                bf[n] = *(const v4i*)(smB[BUF] +                                \
                        (wc * 64 + n * 32 + r32) * 64 + ks * 32 + kh);          \
            _Pragma("unroll")                                                   \
            for (int m = 0; m < 2; ++m)                                         \
                _Pragma("unroll")                                               \
                for (int n = 0; n < 2; ++n)                                     \
                    acc[m][n] = __builtin_amdgcn_mfma_i32_32x32x32_i8(          \
                        af[m], bf[n], acc[m][n], 0, 0, 0);                      \
        }                                                                       \
    } while (0)

    // 16 K-tiles of 64. Prologue stages tile 0; steady state: stage t+1,
    // compute t, __syncthreads (vmcnt drain overlaps compute).
    STAGE(0, 0);
    __syncthreads();
#pragma unroll 1
    for (int kt = 0; kt < 7; ++kt) {
        STAGE(1, (2 * kt + 1) * 64);
        COMPUTE(0);
        __syncthreads();
        STAGE(0, (2 * kt + 2) * 64);
        COMPUTE(1);
        __syncthreads();
    }
    STAGE(1, 15 * 64);
    COMPUTE(0);
    __syncthreads();
    COMPUTE(1);
#undef STAGE
#undef COMPUTE

    // epilogue: 32x32 C/D map col=lane&31, row=(reg&3)+8*(reg>>2)+4*(lane>>5)
    const int col = lane & 31;
    const int rb = 4 * (lane >> 5);
    float wsc[2], bv[2];
    int gcolv[2];
#pragma unroll
    for (int n = 0; n < 2; ++n) {
        gcolv[n] = bn * 128 + wc * 64 + n * 32 + col;
        wsc[n] = wscale[gcolv[n]];
        bv[n] = bias[gcolv[n]];
    }
#pragma unroll
    for (int m = 0; m < 2; ++m) {
#pragma unroll
        for (int j = 0; j < 16; ++j) {
            const int grow = bm * 128 + wr * 64 + m * 32 + (j & 3) + 8 * (j >> 2) + rb;
            const float is = xscale[grow];
#pragma unroll
            for (int n = 0; n < 2; ++n) {
                out[(size_t)grow * OUT_DIM + gcolv[n]] =
                    is * wsc[n] * ((float)acc[m][n][j] + bv[n]);
            }
        }
    }
}

extern "C" void kernel_launch(void* const* d_in, const int* in_sizes, int n_in,
                              void* d_out, int out_size, void* d_ws, size_t ws_size,
                              hipStream_t stream) {
    const float* x = (const float*)d_in[0];
    const float* w = (const float*)d_in[1];
    const float* g = (const float*)d_in[2];
    const float* bias = (const float*)d_in[3];
    float* out = (float*)d_out;

    // workspace layout (16B-aligned)
    signed char* sx = (signed char*)d_ws;                       // 33554432 B
    signed char* wb = sx + (size_t)B_DIM * IN_DIM;              //  1048576 B
    float* xscale = (float*)(wb + (size_t)OUT_DIM * IN_DIM);    //   131072 B
    float* wscale = xscale + B_DIM;                             //     4096 B

    prep_kernel<<<B_DIM / 4 + OUT_DIM / 4, 256, 0, stream>>>(x, w, g, sx, wb,
                                                             xscale, wscale);
    gemm_i8_kernel<<<(B_DIM / 128) * (OUT_DIM / 128), 256, 0, stream>>>(
        sx, wb, xscale, wscale, bias, out);
}